// Round 4
// baseline (182.427 us; speedup 1.0000x reference)
//
#include <hip/hip_runtime.h>

#define BLOCK 256

typedef float f4a __attribute__((ext_vector_type(4)));              // 16B-aligned float4
typedef float f4u __attribute__((ext_vector_type(4), aligned(4)));  // 4B-aligned float4

// R4: ONE WAVE PER SAMPLE. No LDS, no __syncthreads, 4x work per wave vs R3,
// samples assigned in launch order so co-resident waves stream address-
// adjacent rows (DRAM/L2 temporal locality). x/w made 16B-aligned via <=3
// element prologue; y read as 4B-aligned dwordx4.
__global__ __launch_bounds__(BLOCK) void chi2_per_sample(
    const float* __restrict__ fluct,
    const float* __restrict__ ivar,
    const float* __restrict__ outp,
    const int*  __restrict__ ovl,      // (B,4) int32: s_in, e_in, s_out, e_out
    float* __restrict__ partial,
    int L)
{
    const int wave = (blockIdx.x * BLOCK + threadIdx.x) >> 6;  // global wave id = sample
    const int lane = threadIdx.x & 63;

    const int s_in  = ovl[wave * 4 + 0];
    const int e_in  = ovl[wave * 4 + 1];
    const int s_out = ovl[wave * 4 + 2];
    const int len   = e_in - s_in;

    const float* __restrict__ xp = fluct + (size_t)wave * L + s_in;
    const float* __restrict__ wp = ivar  + (size_t)wave * L + s_in;
    const float* __restrict__ yp = outp  + (size_t)wave * L + s_out;

    // Prologue: bring xp/wp to 16B alignment (row base is 16B-aligned since
    // L % 4 == 0, so misalignment is s_in & 3; len >= 1024 > 3).
    const int align = (4 - (s_in & 3)) & 3;

    float acc = 0.f;
    if (lane < align) {
        const float d = xp[lane] - yp[lane];
        acc = fmaf(d * d, wp[lane], acc);
    }

    const int n4 = (len - align) >> 2;          // in [255, 768]
    const f4a* __restrict__ x4 = reinterpret_cast<const f4a*>(xp + align);
    const f4a* __restrict__ w4 = reinterpret_cast<const f4a*>(wp + align);
    const float* __restrict__ yb = yp + align;

    float a0 = 0.f, a1 = 0.f, a2 = 0.f, a3 = 0.f;
    int c = lane;
    // Main: 4 chunks x 3 streams = 12 wide loads in flight per wave.
    for (; c + 192 < n4; c += 256) {
        const f4a xv0 = x4[c];
        const f4a xv1 = x4[c +  64];
        const f4a xv2 = x4[c + 128];
        const f4a xv3 = x4[c + 192];
        const f4u yv0 = *reinterpret_cast<const f4u*>(yb + 4 * c);
        const f4u yv1 = *reinterpret_cast<const f4u*>(yb + 4 * (c +  64));
        const f4u yv2 = *reinterpret_cast<const f4u*>(yb + 4 * (c + 128));
        const f4u yv3 = *reinterpret_cast<const f4u*>(yb + 4 * (c + 192));
        const f4a wv0 = w4[c];
        const f4a wv1 = w4[c +  64];
        const f4a wv2 = w4[c + 128];
        const f4a wv3 = w4[c + 192];
        #pragma unroll
        for (int e = 0; e < 4; ++e) {
            const float d0 = xv0[e] - yv0[e];
            const float d1 = xv1[e] - yv1[e];
            const float d2 = xv2[e] - yv2[e];
            const float d3 = xv3[e] - yv3[e];
            a0 = fmaf(d0 * d0, wv0[e], a0);
            a1 = fmaf(d1 * d1, wv1[e], a1);
            a2 = fmaf(d2 * d2, wv2[e], a2);
            a3 = fmaf(d3 * d3, wv3[e], a3);
        }
    }
    // Remainder chunks (<=3 strided iterations; last one lane-divergent).
    for (; c < n4; c += 64) {
        const f4a xv = x4[c];
        const f4u yv = *reinterpret_cast<const f4u*>(yb + 4 * c);
        const f4a wv = w4[c];
        #pragma unroll
        for (int e = 0; e < 4; ++e) {
            const float d = xv[e] - yv[e];
            a0 = fmaf(d * d, wv[e], a0);
        }
    }
    // Scalar tail: 0..3 elements past the last full chunk.
    const int done = align + (n4 << 2);
    const int rem  = len - done;
    if (lane < rem) {
        const float d = xp[done + lane] - yp[done + lane];
        acc = fmaf(d * d, wp[done + lane], acc);
    }

    acc += (a0 + a1) + (a2 + a3);

    // wave=64 shuffle reduction, no LDS, no barrier
    #pragma unroll
    for (int off = 32; off > 0; off >>= 1)
        acc += __shfl_down(acc, off, 64);

    if (lane == 0)
        partial[wave] = acc / (float)len;
}

// Single-block mean over B partials.
__global__ __launch_bounds__(BLOCK) void chi2_reduce_mean(
    const float* __restrict__ partial, float* __restrict__ out, int B)
{
    float acc = 0.f;
    for (int i = threadIdx.x; i < B; i += BLOCK) acc += partial[i];

    #pragma unroll
    for (int off = 32; off > 0; off >>= 1)
        acc += __shfl_down(acc, off, 64);

    __shared__ float sacc[BLOCK / 64];
    if ((threadIdx.x & 63) == 0) sacc[threadIdx.x >> 6] = acc;
    __syncthreads();

    if (threadIdx.x == 0) {
        float s = 0.f;
        #pragma unroll
        for (int i = 0; i < BLOCK / 64; ++i) s += sacc[i];
        out[0] = s / (float)B;
    }
}

extern "C" void kernel_launch(void* const* d_in, const int* in_sizes, int n_in,
                              void* d_out, int out_size, void* d_ws, size_t ws_size,
                              hipStream_t stream) {
    const float* fluct = (const float*)d_in[0];  // (B,1,L) f32
    const float* ivar  = (const float*)d_in[1];  // (B,1,L) f32
    const float* outp  = (const float*)d_in[2];  // (B,1,L) f32
    const int*   ovl   = (const int*)d_in[3];    // (B,4)   i32

    const int B = in_sizes[3] / 4;               // 4096
    const int L = in_sizes[0] / B;               // 4096

    float* partial = (float*)d_ws;  // B floats

    const int waves_per_block = BLOCK / 64;
    chi2_per_sample<<<B / waves_per_block, BLOCK, 0, stream>>>(
        fluct, ivar, outp, ovl, partial, L);
    chi2_reduce_mean<<<1, BLOCK, 0, stream>>>(partial, (float*)d_out, B);
}